// Round 3
// baseline (520.234 us; speedup 1.0000x reference)
//
#include <hip/hip_runtime.h>

#define NN 50000
#define NE 800000
#define ET (NE + NN)

static __device__ __forceinline__ float bf2f(unsigned short u) {
  union { unsigned int i; float f; } v; v.i = ((unsigned int)u) << 16; return v.f;
}
static __device__ __forceinline__ unsigned short f2bf(float f) {
  union { unsigned int i; float f; } v; v.f = f;
  unsigned int r = v.i + 0x7fffu + ((v.i >> 16) & 1u);
  return (unsigned short)(r >> 16);
}
static __device__ __forceinline__ float lrelu(float z) { return z > 0.f ? z : 0.2f * z; }

// ---------------- CSR build ----------------
__global__ void k_count(const int* __restrict__ ei, int* __restrict__ counts) {
  int e = blockIdx.x * blockDim.x + threadIdx.x;
  if (e >= ET) return;
  int dst = (e < NE) ? ei[NE + e] : (e - NE);
  atomicAdd(&counts[dst], 1);
}

__global__ __launch_bounds__(1024) void k_scan(const int* __restrict__ counts,
                                               int* __restrict__ row_ptr,
                                               int* __restrict__ cursor) {
  __shared__ int sa[1024];
  __shared__ int sb[1024];
  const int t = threadIdx.x;
  const int chunk = (NN + 1023) / 1024;  // 49
  const int beg = t * chunk;
  int s = 0;
  for (int i = 0; i < chunk; ++i) {
    int idx = beg + i;
    if (idx < NN) s += counts[idx];
  }
  sa[t] = s;
  __syncthreads();
  int* src = sa;
  int* dstp = sb;
  for (int off = 1; off < 1024; off <<= 1) {
    int v = src[t];
    if (t >= off) v += src[t - off];
    dstp[t] = v;
    int* tmp = src; src = dstp; dstp = tmp;
    __syncthreads();
  }
  int run = (t == 0) ? 0 : src[t - 1];
  for (int i = 0; i < chunk; ++i) {
    int idx = beg + i;
    if (idx < NN) {
      row_ptr[idx] = run;
      cursor[idx] = run;
      run += counts[idx];
    }
  }
  if (t == 1023) row_ptr[NN] = run;
}

__global__ void k_scatter(const int* __restrict__ ei, int* __restrict__ cursor,
                          int* __restrict__ ssrc) {
  int e = blockIdx.x * blockDim.x + threadIdx.x;
  if (e >= ET) return;
  int src = (e < NE) ? ei[e] : (e - NE);
  int dst = (e < NE) ? ei[NE + e] : (e - NE);
  int pos = atomicAdd(&cursor[dst], 1);
  ssrc[pos] = src;
}

// ---------------- Layer-1 GEMM (fp32) + attention scalars ----------------
// h1[N,256] (stored bf16) = x[N,128] @ W1[128,256]; as1/ad1[n,h] = head-dots.
__global__ __launch_bounds__(256) void k_gemm1(
    const float* __restrict__ x, const float* __restrict__ W1,
    const float* __restrict__ a1s, const float* __restrict__ a1d,
    unsigned short* __restrict__ h1, float* __restrict__ as1, float* __restrict__ ad1) {
  __shared__ float xst[128][32];    // transposed x tile [k][row], 16 KB
  __shared__ float wtf[32 * 256];   // W1 k-tile, 32 KB
  __shared__ float asl[32][8];
  __shared__ float adl[32][8];
  const int tid = threadIdx.x;
  const int row0 = blockIdx.x * 32;
  // stage x tile (32 rows x 128 cols), transposed into LDS
  {
    int r = tid >> 3;
    int cs = (tid & 7) * 16;
    int row = row0 + r;
    float tmp[16];
    if (row < NN) {
      const float4* p = (const float4*)(x + (size_t)row * 128 + cs);
      float4 v0 = p[0], v1 = p[1], v2 = p[2], v3 = p[3];
      tmp[0] = v0.x; tmp[1] = v0.y; tmp[2] = v0.z; tmp[3] = v0.w;
      tmp[4] = v1.x; tmp[5] = v1.y; tmp[6] = v1.z; tmp[7] = v1.w;
      tmp[8] = v2.x; tmp[9] = v2.y; tmp[10] = v2.z; tmp[11] = v2.w;
      tmp[12] = v3.x; tmp[13] = v3.y; tmp[14] = v3.z; tmp[15] = v3.w;
    } else {
      for (int j = 0; j < 16; ++j) tmp[j] = 0.f;
    }
    for (int j = 0; j < 16; ++j) xst[cs + j][r] = tmp[j];
  }
  ((float*)asl)[tid] = 0.f;
  ((float*)adl)[tid] = 0.f;

  const int cg = tid & 31, rg = tid >> 5;
  const int c0 = cg * 8, r0 = rg * 4;
  float acc[4][8];
  for (int i = 0; i < 4; ++i)
    for (int j = 0; j < 8; ++j) acc[i][j] = 0.f;

  for (int kt = 0; kt < 4; ++kt) {
    __syncthreads();
    for (int i = tid; i < 2048; i += 256)
      ((float4*)wtf)[i] = ((const float4*)(W1 + kt * 8192))[i];
    __syncthreads();
    for (int k = 0; k < 32; ++k) {
      const int kk = kt * 32 + k;
      float4 xv = *(const float4*)&xst[kk][r0];
      float xf[4] = {xv.x, xv.y, xv.z, xv.w};
      float4 w0 = *(const float4*)&wtf[k * 256 + c0];
      float4 w1v = *(const float4*)&wtf[k * 256 + c0 + 4];
      float wf[8] = {w0.x, w0.y, w0.z, w0.w, w1v.x, w1v.y, w1v.z, w1v.w};
      for (int i = 0; i < 4; ++i)
        for (int j = 0; j < 8; ++j) acc[i][j] = fmaf(xf[i], wf[j], acc[i][j]);
    }
  }
  // epilogue: store h1 (bf16), accumulate attention scalars per (row, head)
  float a1sv[8], a1dv[8];
  for (int j = 0; j < 8; ++j) {
    a1sv[j] = a1s[c0 + j];
    a1dv[j] = a1d[c0 + j];
  }
  const int g = c0 >> 5;  // head of this 8-col group
  for (int i = 0; i < 4; ++i) {
    int row = row0 + r0 + i;
    float pa = 0.f, pd = 0.f;
    for (int j = 0; j < 8; ++j) {
      pa = fmaf(acc[i][j], a1sv[j], pa);
      pd = fmaf(acc[i][j], a1dv[j], pd);
    }
    if (row < NN) {
      unsigned short h8[8];
      for (int j = 0; j < 8; ++j) h8[j] = f2bf(acc[i][j]);
      uint4 o;
      o.x = (unsigned int)h8[0] | ((unsigned int)h8[1] << 16);
      o.y = (unsigned int)h8[2] | ((unsigned int)h8[3] << 16);
      o.z = (unsigned int)h8[4] | ((unsigned int)h8[5] << 16);
      o.w = (unsigned int)h8[6] | ((unsigned int)h8[7] << 16);
      *(uint4*)(h1 + (size_t)row * 256 + c0) = o;
    }
    atomicAdd(&asl[r0 + i][g], pa);
    atomicAdd(&adl[r0 + i][g], pd);
  }
  __syncthreads();
  {
    int r = tid >> 3, h = tid & 7;
    int row = row0 + r;
    if (row < NN) {
      as1[(size_t)row * 8 + h] = asl[r][h];
      ad1[(size_t)row * 8 + h] = adl[r][h];
    }
  }
}

// ---------------- Layer-1 aggregation (wave per dst) + fused ELU + W2 + a2 dots ----------------
__global__ __launch_bounds__(256) void k_agg1(
    const int* __restrict__ row_ptr, const int* __restrict__ ssrc,
    const unsigned short* __restrict__ h1, const float* __restrict__ as1,
    const float* __restrict__ ad1, const float* __restrict__ b1,
    const float* __restrict__ W2, const float* __restrict__ a2s,
    const float* __restrict__ a2d, float* __restrict__ t_out,
    float* __restrict__ s2_out, float* __restrict__ d2_out) {
  const int lane = threadIdx.x & 63;
  const int dst = (int)((blockIdx.x * blockDim.x + threadIdx.x) >> 6);
  if (dst >= NN) return;  // wave-uniform
  const int start = row_ptr[dst], end = row_ptr[dst + 1];
  const int hA = lane & 7;
  const int eoff = lane >> 3;
  const float ad_h = ad1[(size_t)dst * 8 + hA];
  // pass 1: softmax denominator (no max-shift: logits bounded, exp-safe)
  float s_loc = 0.f;
  for (int base = start; base < end; base += 8) {
    int e = base + eoff;
    if (e < end) {
      int src = ssrc[e];
      s_loc += __expf(lrelu(as1[(size_t)src * 8 + hA] + ad_h));
    }
  }
  s_loc += __shfl_xor(s_loc, 8);
  s_loc += __shfl_xor(s_loc, 16);
  s_loc += __shfl_xor(s_loc, 32);
  const float inv_sA = 1.f / (s_loc + 1e-16f);
  // pass 2: weighted gather-accumulate; lane owns (head hB, 4 channels at cB)
  const int hB = lane >> 3;
  const int cB = (lane & 7) * 4;
  float acc0 = 0.f, acc1 = 0.f, acc2 = 0.f, acc3 = 0.f;
  for (int base = start; base < end; base += 8) {
    int e = base + eoff;
    int srcv = 0;
    float wv = 0.f;
    if (e < end) {
      srcv = ssrc[e];
      wv = __expf(lrelu(as1[(size_t)srcv * 8 + hA] + ad_h)) * inv_sA;
    }
    int m = end - base;
    if (m > 8) m = 8;
    for (int stp = 0; stp < m; ++stp) {
      int se = __shfl(srcv, stp * 8);
      float w = __shfl(wv, stp * 8 + hB);
      const unsigned short* p = h1 + (size_t)se * 256 + hB * 32 + cB;
      uint2 u = *(const uint2*)p;  // wave reads full contiguous 512B row
      acc0 = fmaf(w, bf2f((unsigned short)(u.x & 0xffffu)), acc0);
      acc1 = fmaf(w, bf2f((unsigned short)(u.x >> 16)), acc1);
      acc2 = fmaf(w, bf2f((unsigned short)(u.y & 0xffffu)), acc2);
      acc3 = fmaf(w, bf2f((unsigned short)(u.y >> 16)), acc3);
    }
  }
  // fused epilogue: +b1, ELU, x@W2 (256->2), a2 dots
  const int col = hB * 32 + cB;
  float av[4] = {acc0, acc1, acc2, acc3};
  float tp0 = 0.f, tp1 = 0.f;
  for (int j = 0; j < 4; ++j) {
    float v = av[j] + b1[col + j];
    v = v > 0.f ? v : (__expf(v) - 1.f);  // ELU
    tp0 = fmaf(v, W2[(col + j) * 2 + 0], tp0);
    tp1 = fmaf(v, W2[(col + j) * 2 + 1], tp1);
  }
  for (int off = 32; off >= 1; off >>= 1) {
    tp0 += __shfl_xor(tp0, off);
    tp1 += __shfl_xor(tp1, off);
  }
  if (lane == 0) {
    t_out[(size_t)dst * 2 + 0] = tp0;
    t_out[(size_t)dst * 2 + 1] = tp1;
    s2_out[dst] = tp0 * a2s[0] + tp1 * a2s[1];
    d2_out[dst] = tp0 * a2d[0] + tp1 * a2d[1];
  }
}

// ---------------- Layer-2 aggregation (thread per dst) ----------------
__global__ void k_agg2(const int* __restrict__ row_ptr, const int* __restrict__ ssrc,
                       const float* __restrict__ t_in, const float* __restrict__ s2,
                       const float* __restrict__ d2, const float* __restrict__ b2,
                       float* __restrict__ out) {
  int n = blockIdx.x * blockDim.x + threadIdx.x;
  if (n >= NN) return;
  int st = row_ptr[n], en = row_ptr[n + 1];
  float dv = d2[n];
  float ssum = 0.f;
  for (int e = st; e < en; ++e) ssum += __expf(lrelu(s2[ssrc[e]] + dv));
  float inv = 1.f / (ssum + 1e-16f);
  float o0 = 0.f, o1 = 0.f;
  for (int e = st; e < en; ++e) {
    int s = ssrc[e];
    float w = __expf(lrelu(s2[s] + dv)) * inv;
    o0 = fmaf(w, t_in[(size_t)s * 2 + 0], o0);
    o1 = fmaf(w, t_in[(size_t)s * 2 + 1], o1);
  }
  out[(size_t)n * 2 + 0] = o0 + b2[0];
  out[(size_t)n * 2 + 1] = o1 + b2[1];
}

extern "C" void kernel_launch(void* const* d_in, const int* in_sizes, int n_in,
                              void* d_out, int out_size, void* d_ws, size_t ws_size,
                              hipStream_t stream) {
  const float* x = (const float*)d_in[0];
  const int* ei = (const int*)d_in[1];
  // d_in[2] = batch (unused)
  const float* W1 = (const float*)d_in[3];
  const float* a1s = (const float*)d_in[4];
  const float* a1d = (const float*)d_in[5];
  const float* b1 = (const float*)d_in[6];
  const float* W2 = (const float*)d_in[7];
  const float* a2s = (const float*)d_in[8];
  const float* a2d = (const float*)d_in[9];
  const float* b2 = (const float*)d_in[10];
  float* out = (float*)d_out;

  char* ws = (char*)d_ws;
  size_t off = 0;
  auto alloc = [&](size_t bytes) -> void* {
    void* p = ws + off;
    off += (bytes + 255) & ~(size_t)255;
    return p;
  };
  int* counts = (int*)alloc((size_t)NN * 4);
  int* row_ptr = (int*)alloc((size_t)(NN + 1) * 4);
  int* cursor = (int*)alloc((size_t)NN * 4);
  int* ssrc = (int*)alloc((size_t)ET * 4);
  unsigned short* h1 = (unsigned short*)alloc((size_t)NN * 256 * 2);
  float* as1 = (float*)alloc((size_t)NN * 8 * 4);
  float* ad1 = (float*)alloc((size_t)NN * 8 * 4);
  float* t = (float*)alloc((size_t)NN * 2 * 4);
  float* s2 = (float*)alloc((size_t)NN * 4);
  float* d2v = (float*)alloc((size_t)NN * 4);
  (void)ws_size; (void)in_sizes; (void)n_in; (void)out_size;

  hipMemsetAsync(counts, 0, (size_t)NN * 4, stream);
  k_count<<<(ET + 255) / 256, 256, 0, stream>>>(ei, counts);
  k_scan<<<1, 1024, 0, stream>>>(counts, row_ptr, cursor);
  k_scatter<<<(ET + 255) / 256, 256, 0, stream>>>(ei, cursor, ssrc);
  k_gemm1<<<(NN + 31) / 32, 256, 0, stream>>>(x, W1, a1s, a1d, h1, as1, ad1);
  k_agg1<<<(NN + 3) / 4, 256, 0, stream>>>(row_ptr, ssrc, h1, as1, ad1, b1, W2, a2s, a2d, t, s2, d2v);
  k_agg2<<<(NN + 255) / 256, 256, 0, stream>>>(row_ptr, ssrc, t, s2, d2v, b2, out);
}

// Round 4
// 410.290 us; speedup vs baseline: 1.2680x; 1.2680x over previous
//
#include <hip/hip_runtime.h>

#define NN 50000
#define NE 800000
#define ET (NE + NN)
#define SCAN_B ((NN + 255) / 256)  // 196 blocks

static __device__ __forceinline__ float bf2f(unsigned short u) {
  union { unsigned int i; float f; } v; v.i = ((unsigned int)u) << 16; return v.f;
}
static __device__ __forceinline__ unsigned short f2bf(float f) {
  union { unsigned int i; float f; } v; v.f = f;
  unsigned int r = v.i + 0x7fffu + ((v.i >> 16) & 1u);
  return (unsigned short)(r >> 16);
}
static __device__ __forceinline__ float lrelu(float z) { return z > 0.f ? z : 0.2f * z; }

// ---------------- CSR build ----------------
__global__ void k_count(const int* __restrict__ ei, int* __restrict__ counts) {
  int e = blockIdx.x * blockDim.x + threadIdx.x;
  if (e >= ET) return;
  int dst = (e < NE) ? ei[NE + e] : (e - NE);
  atomicAdd(&counts[dst], 1);
}

// stage a: per-block 256-wide scan; pre[i] = block-local exclusive prefix, bsum[b] = block total
__global__ __launch_bounds__(256) void k_scan_a(const int* __restrict__ counts,
                                                int* __restrict__ pre, int* __restrict__ bsum) {
  __shared__ int sa[256];
  __shared__ int sb[256];
  const int t = threadIdx.x;
  const int i = blockIdx.x * 256 + t;
  sa[t] = (i < NN) ? counts[i] : 0;
  __syncthreads();
  int* src = sa;
  int* dst = sb;
  for (int off = 1; off < 256; off <<= 1) {
    int v = src[t];
    if (t >= off) v += src[t - off];
    dst[t] = v;
    int* tmp = src; src = dst; dst = tmp;
    __syncthreads();
  }
  int excl = (t == 0) ? 0 : src[t - 1];
  if (i < NN) pre[i] = excl;
  if (t == 255) bsum[blockIdx.x] = src[255];
}

// stage b: scan the 196 block sums (single block); bsum becomes exclusive offsets
__global__ __launch_bounds__(256) void k_scan_b(int* __restrict__ bsum, int* __restrict__ row_ptr) {
  __shared__ int sa[256];
  __shared__ int sb[256];
  const int t = threadIdx.x;
  sa[t] = (t < SCAN_B) ? bsum[t] : 0;
  __syncthreads();
  int* src = sa;
  int* dst = sb;
  for (int off = 1; off < 256; off <<= 1) {
    int v = src[t];
    if (t >= off) v += src[t - off];
    dst[t] = v;
    int* tmp = src; src = dst; dst = tmp;
    __syncthreads();
  }
  int excl = (t == 0) ? 0 : src[t - 1];
  if (t < SCAN_B) bsum[t] = excl;
  if (t == 255) row_ptr[NN] = src[255];
}

// stage c: global prefix = block offset + local prefix
__global__ __launch_bounds__(256) void k_scan_c(const int* __restrict__ pre,
                                                const int* __restrict__ bsum,
                                                int* __restrict__ row_ptr,
                                                int* __restrict__ cursor) {
  int i = blockIdx.x * 256 + threadIdx.x;
  if (i >= NN) return;
  int v = bsum[blockIdx.x] + pre[i];
  row_ptr[i] = v;
  cursor[i] = v;
}

__global__ void k_scatter(const int* __restrict__ ei, int* __restrict__ cursor,
                          int* __restrict__ ssrc) {
  int e = blockIdx.x * blockDim.x + threadIdx.x;
  if (e >= ET) return;
  int src = (e < NE) ? ei[e] : (e - NE);
  int dst = (e < NE) ? ei[NE + e] : (e - NE);
  int pos = atomicAdd(&cursor[dst], 1);
  ssrc[pos] = src;
}

// ---------------- Layer-1 GEMM (fp32) + attention scalars ----------------
// h1[N,256] (stored bf16) = x[N,128] @ W1[128,256]; as1/ad1[n,h] = head-dots.
__global__ __launch_bounds__(256) void k_gemm1(
    const float* __restrict__ x, const float* __restrict__ W1,
    const float* __restrict__ a1s, const float* __restrict__ a1d,
    unsigned short* __restrict__ h1, float* __restrict__ as1, float* __restrict__ ad1) {
  __shared__ float xst[128][32];    // transposed x tile [k][row], 16 KB
  __shared__ float wtf[32 * 256];   // W1 k-tile, 32 KB
  __shared__ float asl[32][8];
  __shared__ float adl[32][8];
  const int tid = threadIdx.x;
  const int row0 = blockIdx.x * 32;
  {
    int r = tid >> 3;
    int cs = (tid & 7) * 16;
    int row = row0 + r;
    float tmp[16];
    if (row < NN) {
      const float4* p = (const float4*)(x + (size_t)row * 128 + cs);
      float4 v0 = p[0], v1 = p[1], v2 = p[2], v3 = p[3];
      tmp[0] = v0.x; tmp[1] = v0.y; tmp[2] = v0.z; tmp[3] = v0.w;
      tmp[4] = v1.x; tmp[5] = v1.y; tmp[6] = v1.z; tmp[7] = v1.w;
      tmp[8] = v2.x; tmp[9] = v2.y; tmp[10] = v2.z; tmp[11] = v2.w;
      tmp[12] = v3.x; tmp[13] = v3.y; tmp[14] = v3.z; tmp[15] = v3.w;
    } else {
      for (int j = 0; j < 16; ++j) tmp[j] = 0.f;
    }
    for (int j = 0; j < 16; ++j) xst[cs + j][r] = tmp[j];
  }
  ((float*)asl)[tid] = 0.f;
  ((float*)adl)[tid] = 0.f;

  const int cg = tid & 31, rg = tid >> 5;
  const int c0 = cg * 8, r0 = rg * 4;
  float acc[4][8];
  for (int i = 0; i < 4; ++i)
    for (int j = 0; j < 8; ++j) acc[i][j] = 0.f;

  for (int kt = 0; kt < 4; ++kt) {
    __syncthreads();
    for (int i = tid; i < 2048; i += 256)
      ((float4*)wtf)[i] = ((const float4*)(W1 + kt * 8192))[i];
    __syncthreads();
    for (int k = 0; k < 32; ++k) {
      const int kk = kt * 32 + k;
      float4 xv = *(const float4*)&xst[kk][r0];
      float xf[4] = {xv.x, xv.y, xv.z, xv.w};
      float4 w0 = *(const float4*)&wtf[k * 256 + c0];
      float4 w1v = *(const float4*)&wtf[k * 256 + c0 + 4];
      float wf[8] = {w0.x, w0.y, w0.z, w0.w, w1v.x, w1v.y, w1v.z, w1v.w};
      for (int i = 0; i < 4; ++i)
        for (int j = 0; j < 8; ++j) acc[i][j] = fmaf(xf[i], wf[j], acc[i][j]);
    }
  }
  float a1sv[8], a1dv[8];
  for (int j = 0; j < 8; ++j) {
    a1sv[j] = a1s[c0 + j];
    a1dv[j] = a1d[c0 + j];
  }
  const int g = c0 >> 5;
  for (int i = 0; i < 4; ++i) {
    int row = row0 + r0 + i;
    float pa = 0.f, pd = 0.f;
    for (int j = 0; j < 8; ++j) {
      pa = fmaf(acc[i][j], a1sv[j], pa);
      pd = fmaf(acc[i][j], a1dv[j], pd);
    }
    if (row < NN) {
      unsigned short h8[8];
      for (int j = 0; j < 8; ++j) h8[j] = f2bf(acc[i][j]);
      uint4 o;
      o.x = (unsigned int)h8[0] | ((unsigned int)h8[1] << 16);
      o.y = (unsigned int)h8[2] | ((unsigned int)h8[3] << 16);
      o.z = (unsigned int)h8[4] | ((unsigned int)h8[5] << 16);
      o.w = (unsigned int)h8[6] | ((unsigned int)h8[7] << 16);
      *(uint4*)(h1 + (size_t)row * 256 + c0) = o;
    }
    atomicAdd(&asl[r0 + i][g], pa);
    atomicAdd(&adl[r0 + i][g], pd);
  }
  __syncthreads();
  {
    int r = tid >> 3, h = tid & 7;
    int row = row0 + r;
    if (row < NN) {
      as1[(size_t)row * 8 + h] = asl[r][h];
      ad1[(size_t)row * 8 + h] = adl[r][h];
    }
  }
}

// ---------------- Layer-1 aggregation (wave per dst) + fused ELU + W2 + a2 dots ----------------
__global__ __launch_bounds__(256) void k_agg1(
    const int* __restrict__ row_ptr, const int* __restrict__ ssrc,
    const unsigned short* __restrict__ h1, const float* __restrict__ as1,
    const float* __restrict__ ad1, const float* __restrict__ b1,
    const float* __restrict__ W2, const float* __restrict__ a2s,
    const float* __restrict__ a2d, float* __restrict__ t_out,
    float* __restrict__ s2_out, float* __restrict__ d2_out) {
  const int lane = threadIdx.x & 63;
  const int dst = (int)((blockIdx.x * blockDim.x + threadIdx.x) >> 6);
  if (dst >= NN) return;  // wave-uniform
  const int start = row_ptr[dst], end = row_ptr[dst + 1];
  const int hA = lane & 7;
  const int eoff = lane >> 3;
  const float ad_h = ad1[(size_t)dst * 8 + hA];
  float s_loc = 0.f;
  for (int base = start; base < end; base += 8) {
    int e = base + eoff;
    if (e < end) {
      int src = ssrc[e];
      s_loc += __expf(lrelu(as1[(size_t)src * 8 + hA] + ad_h));
    }
  }
  s_loc += __shfl_xor(s_loc, 8);
  s_loc += __shfl_xor(s_loc, 16);
  s_loc += __shfl_xor(s_loc, 32);
  const float inv_sA = 1.f / (s_loc + 1e-16f);
  const int hB = lane >> 3;
  const int cB = (lane & 7) * 4;
  float acc0 = 0.f, acc1 = 0.f, acc2 = 0.f, acc3 = 0.f;
  for (int base = start; base < end; base += 8) {
    int e = base + eoff;
    int srcv = 0;
    float wv = 0.f;
    if (e < end) {
      srcv = ssrc[e];
      wv = __expf(lrelu(as1[(size_t)srcv * 8 + hA] + ad_h)) * inv_sA;
    }
    int m = end - base;
    if (m > 8) m = 8;
    for (int stp = 0; stp < m; ++stp) {
      int se = __shfl(srcv, stp * 8);
      float w = __shfl(wv, stp * 8 + hB);
      const unsigned short* p = h1 + (size_t)se * 256 + hB * 32 + cB;
      uint2 u = *(const uint2*)p;
      acc0 = fmaf(w, bf2f((unsigned short)(u.x & 0xffffu)), acc0);
      acc1 = fmaf(w, bf2f((unsigned short)(u.x >> 16)), acc1);
      acc2 = fmaf(w, bf2f((unsigned short)(u.y & 0xffffu)), acc2);
      acc3 = fmaf(w, bf2f((unsigned short)(u.y >> 16)), acc3);
    }
  }
  const int col = hB * 32 + cB;
  float av[4] = {acc0, acc1, acc2, acc3};
  float tp0 = 0.f, tp1 = 0.f;
  for (int j = 0; j < 4; ++j) {
    float v = av[j] + b1[col + j];
    v = v > 0.f ? v : (__expf(v) - 1.f);  // ELU
    tp0 = fmaf(v, W2[(col + j) * 2 + 0], tp0);
    tp1 = fmaf(v, W2[(col + j) * 2 + 1], tp1);
  }
  for (int off = 32; off >= 1; off >>= 1) {
    tp0 += __shfl_xor(tp0, off);
    tp1 += __shfl_xor(tp1, off);
  }
  if (lane == 0) {
    t_out[(size_t)dst * 2 + 0] = tp0;
    t_out[(size_t)dst * 2 + 1] = tp1;
    s2_out[dst] = tp0 * a2s[0] + tp1 * a2s[1];
    d2_out[dst] = tp0 * a2d[0] + tp1 * a2d[1];
  }
}

// ---------------- Layer-2 aggregation (thread per dst) ----------------
__global__ void k_agg2(const int* __restrict__ row_ptr, const int* __restrict__ ssrc,
                       const float* __restrict__ t_in, const float* __restrict__ s2,
                       const float* __restrict__ d2, const float* __restrict__ b2,
                       float* __restrict__ out) {
  int n = blockIdx.x * blockDim.x + threadIdx.x;
  if (n >= NN) return;
  int st = row_ptr[n], en = row_ptr[n + 1];
  float dv = d2[n];
  float ssum = 0.f;
  for (int e = st; e < en; ++e) ssum += __expf(lrelu(s2[ssrc[e]] + dv));
  float inv = 1.f / (ssum + 1e-16f);
  float o0 = 0.f, o1 = 0.f;
  for (int e = st; e < en; ++e) {
    int s = ssrc[e];
    float w = __expf(lrelu(s2[s] + dv)) * inv;
    o0 = fmaf(w, t_in[(size_t)s * 2 + 0], o0);
    o1 = fmaf(w, t_in[(size_t)s * 2 + 1], o1);
  }
  out[(size_t)n * 2 + 0] = o0 + b2[0];
  out[(size_t)n * 2 + 1] = o1 + b2[1];
}

extern "C" void kernel_launch(void* const* d_in, const int* in_sizes, int n_in,
                              void* d_out, int out_size, void* d_ws, size_t ws_size,
                              hipStream_t stream) {
  const float* x = (const float*)d_in[0];
  const int* ei = (const int*)d_in[1];
  // d_in[2] = batch (unused)
  const float* W1 = (const float*)d_in[3];
  const float* a1s = (const float*)d_in[4];
  const float* a1d = (const float*)d_in[5];
  const float* b1 = (const float*)d_in[6];
  const float* W2 = (const float*)d_in[7];
  const float* a2s = (const float*)d_in[8];
  const float* a2d = (const float*)d_in[9];
  const float* b2 = (const float*)d_in[10];
  float* out = (float*)d_out;

  char* ws = (char*)d_ws;
  size_t off = 0;
  auto alloc = [&](size_t bytes) -> void* {
    void* p = ws + off;
    off += (bytes + 255) & ~(size_t)255;
    return p;
  };
  int* counts = (int*)alloc((size_t)NN * 4);
  int* row_ptr = (int*)alloc((size_t)(NN + 1) * 4);
  int* cursor = (int*)alloc((size_t)NN * 4);
  int* pre = (int*)alloc((size_t)NN * 4);
  int* bsum = (int*)alloc((size_t)SCAN_B * 4);
  int* ssrc = (int*)alloc((size_t)ET * 4);
  unsigned short* h1 = (unsigned short*)alloc((size_t)NN * 256 * 2);
  float* as1 = (float*)alloc((size_t)NN * 8 * 4);
  float* ad1 = (float*)alloc((size_t)NN * 8 * 4);
  float* t = (float*)alloc((size_t)NN * 2 * 4);
  float* s2 = (float*)alloc((size_t)NN * 4);
  float* d2v = (float*)alloc((size_t)NN * 4);
  (void)ws_size; (void)in_sizes; (void)n_in; (void)out_size;

  hipMemsetAsync(counts, 0, (size_t)NN * 4, stream);
  k_count<<<(ET + 255) / 256, 256, 0, stream>>>(ei, counts);
  k_scan_a<<<SCAN_B, 256, 0, stream>>>(counts, pre, bsum);
  k_scan_b<<<1, 256, 0, stream>>>(bsum, row_ptr);
  k_scan_c<<<SCAN_B, 256, 0, stream>>>(pre, bsum, row_ptr, cursor);
  k_scatter<<<(ET + 255) / 256, 256, 0, stream>>>(ei, cursor, ssrc);
  k_gemm1<<<(NN + 31) / 32, 256, 0, stream>>>(x, W1, a1s, a1d, h1, as1, ad1);
  k_agg1<<<(NN + 3) / 4, 256, 0, stream>>>(row_ptr, ssrc, h1, as1, ad1, b1, W2, a2s, a2d, t, s2, d2v);
  k_agg2<<<(NN + 255) / 256, 256, 0, stream>>>(row_ptr, ssrc, t, s2, d2v, b2, out);
}

// Round 5
// 355.400 us; speedup vs baseline: 1.4638x; 1.1544x over previous
//
#include <hip/hip_runtime.h>

#define NN 50000
#define NP 50048  // padded to multiple of 64
#define NE 800000
#define ET (NE + NN)
#define SCAN_B ((NN + 255) / 256)  // 196 blocks

typedef __attribute__((ext_vector_type(8))) short short8;
typedef __attribute__((ext_vector_type(4))) float f32x4;

static __device__ __forceinline__ float bf2f(unsigned short u) {
  union { unsigned int i; float f; } v; v.i = ((unsigned int)u) << 16; return v.f;
}
static __device__ __forceinline__ unsigned short f2bf(float f) {
  union { unsigned int i; float f; } v; v.f = f;
  unsigned int r = v.i + 0x7fffu + ((v.i >> 16) & 1u);
  return (unsigned short)(r >> 16);
}
static __device__ __forceinline__ float lrelu(float z) { return z > 0.f ? z : 0.2f * z; }

// ---------------- bf16x2 split conversions ----------------
__global__ void k_conv_x(const float* __restrict__ x, unsigned short* __restrict__ xh,
                         unsigned short* __restrict__ xl) {
  int i = blockIdx.x * 256 + threadIdx.x;
  if (i >= NP * 128) return;
  int row = i >> 7;
  float v = (row < NN) ? x[i] : 0.f;
  unsigned short hi = f2bf(v);
  xh[i] = hi;
  xl[i] = f2bf(v - bf2f(hi));
}

// W1[128][256] -> Wt_hi/Wt_lo[256][128] (transposed, split)
__global__ void k_conv_w(const float* __restrict__ W1, unsigned short* __restrict__ wh,
                         unsigned short* __restrict__ wl) {
  int i = blockIdx.x * 256 + threadIdx.x;
  if (i >= 32768) return;
  int k = i >> 8, n = i & 255;
  float v = W1[i];
  unsigned short hi = f2bf(v);
  wh[n * 128 + k] = hi;
  wl[n * 128 + k] = f2bf(v - bf2f(hi));
}

// ---------------- CSR build ----------------
__global__ void k_count(const int* __restrict__ ei, int* __restrict__ counts) {
  int e = blockIdx.x * blockDim.x + threadIdx.x;
  if (e >= ET) return;
  int dst = (e < NE) ? ei[NE + e] : (e - NE);
  atomicAdd(&counts[dst], 1);
}

__global__ __launch_bounds__(256) void k_scan_a(const int* __restrict__ counts,
                                                int* __restrict__ pre, int* __restrict__ bsum) {
  __shared__ int sa[256];
  __shared__ int sb[256];
  const int t = threadIdx.x;
  const int i = blockIdx.x * 256 + t;
  sa[t] = (i < NN) ? counts[i] : 0;
  __syncthreads();
  int* src = sa;
  int* dst = sb;
  for (int off = 1; off < 256; off <<= 1) {
    int v = src[t];
    if (t >= off) v += src[t - off];
    dst[t] = v;
    int* tmp = src; src = dst; dst = tmp;
    __syncthreads();
  }
  int excl = (t == 0) ? 0 : src[t - 1];
  if (i < NN) pre[i] = excl;
  if (t == 255) bsum[blockIdx.x] = src[255];
}

__global__ __launch_bounds__(256) void k_scan_b(int* __restrict__ bsum, int* __restrict__ row_ptr) {
  __shared__ int sa[256];
  __shared__ int sb[256];
  const int t = threadIdx.x;
  sa[t] = (t < SCAN_B) ? bsum[t] : 0;
  __syncthreads();
  int* src = sa;
  int* dst = sb;
  for (int off = 1; off < 256; off <<= 1) {
    int v = src[t];
    if (t >= off) v += src[t - off];
    dst[t] = v;
    int* tmp = src; src = dst; dst = tmp;
    __syncthreads();
  }
  int excl = (t == 0) ? 0 : src[t - 1];
  if (t < SCAN_B) bsum[t] = excl;
  if (t == 255) row_ptr[NN] = src[255];
}

__global__ __launch_bounds__(256) void k_scan_c(const int* __restrict__ pre,
                                                const int* __restrict__ bsum,
                                                int* __restrict__ row_ptr,
                                                int* __restrict__ cursor) {
  int i = blockIdx.x * 256 + threadIdx.x;
  if (i >= NN) return;
  int v = bsum[blockIdx.x] + pre[i];
  row_ptr[i] = v;
  cursor[i] = v;
}

__global__ void k_scatter(const int* __restrict__ ei, int* __restrict__ cursor,
                          int* __restrict__ ssrc) {
  int e = blockIdx.x * blockDim.x + threadIdx.x;
  if (e >= ET) return;
  int src = (e < NE) ? ei[e] : (e - NE);
  int dst = (e < NE) ? ei[NE + e] : (e - NE);
  int pos = atomicAdd(&cursor[dst], 1);
  ssrc[pos] = src;
}

// ---------------- Layer-1 GEMM via MFMA bf16x2 (3-pass split) ----------------
// h1[N,256] bf16 = x[N,128] @ W1[128,256]; as1/ad1 from staged tile.
// Wave w of 4: cols [w*64, w*64+64), rows [row0, row0+64).
__global__ __launch_bounds__(256) void k_gemm1(
    const unsigned short* __restrict__ xh, const unsigned short* __restrict__ xl,
    const unsigned short* __restrict__ wh, const unsigned short* __restrict__ wl,
    const float* __restrict__ a1s, const float* __restrict__ a1d,
    unsigned short* __restrict__ h1, float* __restrict__ as1, float* __restrict__ ad1) {
  __shared__ unsigned short hst[64][264];  // 264: 16B-aligned rows, quad-disjoint banks
  const int tid = threadIdx.x;
  const int w = tid >> 6, lane = tid & 63;
  const int quad = lane >> 4, m16 = lane & 15;
  const int row0 = blockIdx.x * 64;
  const int koff = quad * 8;

  f32x4 acc[4][4];
  for (int mt = 0; mt < 4; ++mt)
    for (int nt = 0; nt < 4; ++nt) acc[mt][nt] = (f32x4){0.f, 0.f, 0.f, 0.f};

  for (int kt = 0; kt < 4; ++kt) {
    short8 ah[4], al[4], bh[4], bl[4];
    for (int mt = 0; mt < 4; ++mt) {
      size_t ra = (size_t)(row0 + mt * 16 + m16) * 128 + kt * 32 + koff;
      ah[mt] = *(const short8*)(xh + ra);
      al[mt] = *(const short8*)(xl + ra);
    }
    for (int nt = 0; nt < 4; ++nt) {
      size_t rb = (size_t)(w * 64 + nt * 16 + m16) * 128 + kt * 32 + koff;
      bh[nt] = *(const short8*)(wh + rb);
      bl[nt] = *(const short8*)(wl + rb);
    }
    for (int mt = 0; mt < 4; ++mt)
      for (int nt = 0; nt < 4; ++nt) {
        acc[mt][nt] = __builtin_amdgcn_mfma_f32_16x16x32_bf16(ah[mt], bh[nt], acc[mt][nt], 0, 0, 0);
        acc[mt][nt] = __builtin_amdgcn_mfma_f32_16x16x32_bf16(ah[mt], bl[nt], acc[mt][nt], 0, 0, 0);
        acc[mt][nt] = __builtin_amdgcn_mfma_f32_16x16x32_bf16(al[mt], bh[nt], acc[mt][nt], 0, 0, 0);
      }
  }
  // stage D to LDS (bf16). D layout: col = lane&15, row = quad*4 + reg.
  for (int mt = 0; mt < 4; ++mt)
    for (int nt = 0; nt < 4; ++nt) {
      int c = w * 64 + nt * 16 + m16;
      int rb = mt * 16 + quad * 4;
      for (int r = 0; r < 4; ++r) hst[rb + r][c] = f2bf(acc[mt][nt][r]);
    }
  __syncthreads();
  // coalesced h1 write: 64 rows x 32 uint4
  for (int p = 0; p < 8; ++p) {
    int idx = p * 256 + tid;
    int row = idx >> 5, u4 = idx & 31;
    int grow = row0 + row;
    if (grow < NN) {
      uint4 v = *(const uint4*)&hst[row][u4 * 8];
      *(uint4*)(h1 + (size_t)grow * 256 + u4 * 8) = v;
    }
  }
  // as1/ad1: 64 rows x 8 heads = 512 tasks
  for (int p = 0; p < 2; ++p) {
    int id = p * 256 + tid;
    int row = id >> 3, head = id & 7;
    int grow = row0 + row;
    if (grow < NN) {
      float sa = 0.f, sd = 0.f;
      for (int c = 0; c < 32; ++c) {
        float hv = bf2f(hst[row][head * 32 + c]);
        sa = fmaf(hv, a1s[head * 32 + c], sa);
        sd = fmaf(hv, a1d[head * 32 + c], sd);
      }
      as1[(size_t)grow * 8 + head] = sa;
      ad1[(size_t)grow * 8 + head] = sd;
    }
  }
}

// ---------------- Layer-1 aggregation (wave per dst) + fused ELU + W2 + a2 dots ----------------
__global__ __launch_bounds__(256) void k_agg1(
    const int* __restrict__ row_ptr, const int* __restrict__ ssrc,
    const unsigned short* __restrict__ h1, const float* __restrict__ as1,
    const float* __restrict__ ad1, const float* __restrict__ b1,
    const float* __restrict__ W2, const float* __restrict__ a2s,
    const float* __restrict__ a2d, float* __restrict__ t_out,
    float* __restrict__ s2_out, float* __restrict__ d2_out) {
  const int lane = threadIdx.x & 63;
  const int dst = (int)((blockIdx.x * blockDim.x + threadIdx.x) >> 6);
  if (dst >= NN) return;  // wave-uniform
  const int start = row_ptr[dst], end = row_ptr[dst + 1];
  const int hA = lane & 7;
  const int eoff = lane >> 3;
  const float ad_h = ad1[(size_t)dst * 8 + hA];
  float s_loc = 0.f;
  for (int base = start; base < end; base += 8) {
    int e = base + eoff;
    if (e < end) {
      int src = ssrc[e];
      s_loc += __expf(lrelu(as1[(size_t)src * 8 + hA] + ad_h));
    }
  }
  s_loc += __shfl_xor(s_loc, 8);
  s_loc += __shfl_xor(s_loc, 16);
  s_loc += __shfl_xor(s_loc, 32);
  const float inv_sA = 1.f / (s_loc + 1e-16f);
  const int hB = lane >> 3;
  const int cB = (lane & 7) * 4;
  float acc0 = 0.f, acc1 = 0.f, acc2 = 0.f, acc3 = 0.f;
  for (int base = start; base < end; base += 8) {
    int e = base + eoff;
    int srcv = 0;
    float wv = 0.f;
    if (e < end) {
      srcv = ssrc[e];
      wv = __expf(lrelu(as1[(size_t)srcv * 8 + hA] + ad_h)) * inv_sA;
    }
    int m = end - base;
    if (m > 8) m = 8;
    for (int stp = 0; stp < m; ++stp) {
      int se = __shfl(srcv, stp * 8);
      float w = __shfl(wv, stp * 8 + hB);
      const unsigned short* p = h1 + (size_t)se * 256 + hB * 32 + cB;
      uint2 u = *(const uint2*)p;
      acc0 = fmaf(w, bf2f((unsigned short)(u.x & 0xffffu)), acc0);
      acc1 = fmaf(w, bf2f((unsigned short)(u.x >> 16)), acc1);
      acc2 = fmaf(w, bf2f((unsigned short)(u.y & 0xffffu)), acc2);
      acc3 = fmaf(w, bf2f((unsigned short)(u.y >> 16)), acc3);
    }
  }
  const int col = hB * 32 + cB;
  float av[4] = {acc0, acc1, acc2, acc3};
  float tp0 = 0.f, tp1 = 0.f;
  for (int j = 0; j < 4; ++j) {
    float v = av[j] + b1[col + j];
    v = v > 0.f ? v : (__expf(v) - 1.f);  // ELU
    tp0 = fmaf(v, W2[(col + j) * 2 + 0], tp0);
    tp1 = fmaf(v, W2[(col + j) * 2 + 1], tp1);
  }
  for (int off = 32; off >= 1; off >>= 1) {
    tp0 += __shfl_xor(tp0, off);
    tp1 += __shfl_xor(tp1, off);
  }
  if (lane == 0) {
    t_out[(size_t)dst * 2 + 0] = tp0;
    t_out[(size_t)dst * 2 + 1] = tp1;
    s2_out[dst] = tp0 * a2s[0] + tp1 * a2s[1];
    d2_out[dst] = tp0 * a2d[0] + tp1 * a2d[1];
  }
}

// ---------------- Layer-2 aggregation (thread per dst) ----------------
__global__ void k_agg2(const int* __restrict__ row_ptr, const int* __restrict__ ssrc,
                       const float* __restrict__ t_in, const float* __restrict__ s2,
                       const float* __restrict__ d2, const float* __restrict__ b2,
                       float* __restrict__ out) {
  int n = blockIdx.x * blockDim.x + threadIdx.x;
  if (n >= NN) return;
  int st = row_ptr[n], en = row_ptr[n + 1];
  float dv = d2[n];
  float ssum = 0.f;
  for (int e = st; e < en; ++e) ssum += __expf(lrelu(s2[ssrc[e]] + dv));
  float inv = 1.f / (ssum + 1e-16f);
  float o0 = 0.f, o1 = 0.f;
  for (int e = st; e < en; ++e) {
    int s = ssrc[e];
    float w = __expf(lrelu(s2[s] + dv)) * inv;
    o0 = fmaf(w, t_in[(size_t)s * 2 + 0], o0);
    o1 = fmaf(w, t_in[(size_t)s * 2 + 1], o1);
  }
  out[(size_t)n * 2 + 0] = o0 + b2[0];
  out[(size_t)n * 2 + 1] = o1 + b2[1];
}

extern "C" void kernel_launch(void* const* d_in, const int* in_sizes, int n_in,
                              void* d_out, int out_size, void* d_ws, size_t ws_size,
                              hipStream_t stream) {
  const float* x = (const float*)d_in[0];
  const int* ei = (const int*)d_in[1];
  // d_in[2] = batch (unused)
  const float* W1 = (const float*)d_in[3];
  const float* a1s = (const float*)d_in[4];
  const float* a1d = (const float*)d_in[5];
  const float* b1 = (const float*)d_in[6];
  const float* W2 = (const float*)d_in[7];
  const float* a2s = (const float*)d_in[8];
  const float* a2d = (const float*)d_in[9];
  const float* b2 = (const float*)d_in[10];
  float* out = (float*)d_out;

  char* ws = (char*)d_ws;
  size_t off = 0;
  auto alloc = [&](size_t bytes) -> void* {
    void* p = ws + off;
    off += (bytes + 255) & ~(size_t)255;
    return p;
  };
  int* counts = (int*)alloc((size_t)NN * 4);
  int* row_ptr = (int*)alloc((size_t)(NN + 1) * 4);
  int* cursor = (int*)alloc((size_t)NN * 4);
  int* pre = (int*)alloc((size_t)NN * 4);
  int* bsum = (int*)alloc((size_t)SCAN_B * 4);
  int* ssrc = (int*)alloc((size_t)ET * 4);
  unsigned short* xh = (unsigned short*)alloc((size_t)NP * 128 * 2);
  unsigned short* xl = (unsigned short*)alloc((size_t)NP * 128 * 2);
  unsigned short* wh = (unsigned short*)alloc((size_t)32768 * 2);
  unsigned short* wl = (unsigned short*)alloc((size_t)32768 * 2);
  unsigned short* h1 = (unsigned short*)alloc((size_t)NN * 256 * 2);
  float* as1 = (float*)alloc((size_t)NN * 8 * 4);
  float* ad1 = (float*)alloc((size_t)NN * 8 * 4);
  float* t = (float*)alloc((size_t)NN * 2 * 4);
  float* s2 = (float*)alloc((size_t)NN * 4);
  float* d2v = (float*)alloc((size_t)NN * 4);
  (void)ws_size; (void)in_sizes; (void)n_in; (void)out_size;

  hipMemsetAsync(counts, 0, (size_t)NN * 4, stream);
  k_conv_x<<<(NP * 128 + 255) / 256, 256, 0, stream>>>(x, xh, xl);
  k_conv_w<<<128, 256, 0, stream>>>(W1, wh, wl);
  k_count<<<(ET + 255) / 256, 256, 0, stream>>>(ei, counts);
  k_scan_a<<<SCAN_B, 256, 0, stream>>>(counts, pre, bsum);
  k_scan_b<<<1, 256, 0, stream>>>(bsum, row_ptr);
  k_scan_c<<<SCAN_B, 256, 0, stream>>>(pre, bsum, row_ptr, cursor);
  k_scatter<<<(ET + 255) / 256, 256, 0, stream>>>(ei, cursor, ssrc);
  k_gemm1<<<NP / 64, 256, 0, stream>>>(xh, xl, wh, wl, a1s, a1d, h1, as1, ad1);
  k_agg1<<<(NN + 3) / 4, 256, 0, stream>>>(row_ptr, ssrc, h1, as1, ad1, b1, W2, a2s, a2d, t, s2, d2v);
  k_agg2<<<(NN + 255) / 256, 256, 0, stream>>>(row_ptr, ssrc, t, s2, d2v, b2, out);
}